// Round 11
// baseline (306.539 us; speedup 1.0000x reference)
//
#include <hip/hip_runtime.h>
#include <math.h>

typedef __attribute__((ext_vector_type(4))) float f32x4;
typedef __attribute__((ext_vector_type(2))) float f32x2;
typedef __attribute__((ext_vector_type(4))) short s16x4;

#define LOG2E   1.4426950408889634f
#define EPSV    2.220446049250313e-16f
#define HLOG2PI 0.9189385332046727f

// Schraudolph-to-bf16: U = e128 + MAGIC (f32 add rounds to ulp=1 since
// U in [2^23,2^24)); low16(bits(U)) == bf16 bits of ~2^(e128/128).
// MAGIC = 1.5*2^23 + 127*128 + (128*sigma - 0.5), sigma = -0.0573; folded
// into 'a' at prep time.
#define MAGICC  12599160.0f

static __device__ __forceinline__ float fexp2(float x) {
  return __builtin_amdgcn_exp2f(x);
}

// [hi16(f1)]:[hi16(f0)] -> bf16 trunc pack, one v_perm_b32
static __device__ __forceinline__ unsigned pk_bf16t(float f0, float f1) {
  return __builtin_amdgcn_perm(__builtin_bit_cast(unsigned, f1),
                               __builtin_bit_cast(unsigned, f0), 0x07060302u);
}
// [lo16(u1)]:[lo16(u0)] -> Schraudolph bf16 bits, one v_perm_b32
static __device__ __forceinline__ unsigned pk_lo16(f32x2 u) {
  return __builtin_amdgcn_perm(__builtin_bit_cast(uint2, u).y,
                               __builtin_bit_cast(uint2, u).x, 0x05040100u);
}

static __device__ __forceinline__ float rdlane(float v, int lane) {
  return __builtin_bit_cast(float,
      __builtin_amdgcn_readlane(__builtin_bit_cast(int, v), lane));
}

// ---------------------------------------------------------------------------
// Prep: fold log_softmax(W_logits, axis=1), softplus(pre_sigma), mu into
// per-entry quadratic coefficients scaled by 128*log2(e), Schraudolph magic
// folded into 'a':  U[m,k,j](x) = a + b*x + c*x^2 ; lo16(bits(U)) = bf16(R).
// Layout: group g = m*64 + k*4 + q  (q = j/4) -> 3 consecutive float4 {a,b,c}.
// ---------------------------------------------------------------------------
__global__ void tt_prep(const float* __restrict__ Wl,
                        const float* __restrict__ mu,
                        const float* __restrict__ ps,
                        float* __restrict__ abc, int M) {
  int g = blockIdx.x * blockDim.x + threadIdx.x;
  if (g >= M * 64) return;
  int m = g >> 6;
  int k = (g >> 2) & 15;
  int q = g & 3;
  const float SC = 128.0f * LOG2E;
  float av[4], bv[4], cv[4];
#pragma unroll
  for (int i = 0; i < 4; ++i) {
    int j = q * 4 + i;
    int base = m * 256 + j;               // stride 16 over k'
    float mx = -INFINITY;
    for (int kk = 0; kk < 16; ++kk) mx = fmaxf(mx, Wl[base + kk * 16]);
    float s = 0.f;
    for (int kk = 0; kk < 16; ++kk) s += expf(Wl[base + kk * 16] - mx);
    float lse = mx + logf(s);
    int idx = m * 256 + k * 16 + j;
    float logw = Wl[idx] - lse;
    float p  = ps[idx];
    float sg = (p > 20.f) ? p : log1pf(expf(p));   // softplus
    float inv  = 1.0f / sg;
    float inv2 = inv * inv;
    float muv  = mu[idx];
    av[i] = SC * (logw - logf(sg) - HLOG2PI - 0.5f * muv * muv * inv2) + MAGICC;
    bv[i] = SC * (muv * inv2);
    cv[i] = SC * (-0.5f * inv2);
  }
  f32x4* o = (f32x4*)abc + (long)g * 3;
  o[0] = (f32x4){av[0], av[1], av[2], av[3]};
  o[1] = (f32x4){bv[0], bv[1], bv[2], bv[3]};
  o[2] = (f32x4){cv[0], cv[1], cv[2], cv[3]};
}

// ---------------------------------------------------------------------------
// Specialized main for M == 32. One wave = 16 samples, packed bf16 state.
// KEY CHANGE vs R10: the outer step loop is a REAL loop (#pragma unroll 1,
// 8 trips of 4 steps) instead of fully unrolled. Fully-unrolled variants
// (R5-R10) were 30-60 KB of straight-line code -- at/past the 32 KB per-CU
// I-cache, so every wave continually missed instruction fetch; that matches
// the invariant ~2x gap between static instruction count and wall cycles
// across all previous bodies. This body is ~7 KB (I-cache resident).
// Params advance by pointer increment; next-step prefetch kept (distance =
// 16 sample-iters, covers L2 latency).
// ---------------------------------------------------------------------------
__global__ __launch_bounds__(256, 4)
void tt_main32(const float* __restrict__ X,
               const float* __restrict__ wk0_logits,
               const float* __restrict__ abc,
               float* __restrict__ out, int N) {
  const int l = (int)(threadIdx.x & 63u);
  const int wave = __builtin_amdgcn_readfirstlane((int)(threadIdx.x >> 6));
  const int c = l & 15;   // A row / D col
  const int q = l >> 4;   // quad

  long nb = ((long)blockIdx.x * 4 + wave) * 16;
  if (nb > (long)N - 16) nb = (long)N - 16;   // tail clamp (duplicate work ok)

  // wk0 = softmax(wk0_logits); seed packed state with wk0 (B-frag layout)
  float wl = wk0_logits[c];
  float mx = wl;
#pragma unroll
  for (int d = 1; d < 16; d <<= 1) mx = fmaxf(mx, __shfl_xor(mx, d, 64));
  float ew = fexp2((wl - mx) * LOG2E);
  float sw = ew;
#pragma unroll
  for (int d = 1; d < 16; d <<= 1) sw += __shfl_xor(sw, d, 64);
  float w0 = ew / sw;

  f32x4 q0;
#pragma unroll
  for (int i = 0; i < 4; ++i) q0[i] = __shfl(w0, 4 * q + i, 64);

  uint2 seed;
  seed.x = pk_bf16t(q0[0], q0[1]);
  seed.y = pk_bf16t(q0[2], q0[3]);
  s16x4 Qp[16];
#pragma unroll
  for (int s = 0; s < 16; ++s) Qp[s] = __builtin_bit_cast(s16x4, seed);

  // two vector loads: all 512 x values for this wave (16 samples x 32 steps)
  const float* Xn = X + nb * 32;
  float4 xq0 = *(const float4*)(Xn + l * 4);
  float4 xq1 = *(const float4*)(Xn + 256 + l * 4);

  const int lofs = (c * 4 + q) * 12;        // per-lane float offset into a step
  const float* pp = abc + lofs;             // current-step param pointer
  f32x4 pa = *(const f32x4*)(pp);
  f32x4 pb = *(const f32x4*)(pp + 4);
  f32x4 pc = *(const f32x4*)(pp + 8);
  pp += 768;                                // -> step 1

  const f32x4 zero = (f32x4){0.f, 0.f, 0.f, 0.f};
  const s16x4 clmp = (s16x4){0x0080, 0x0080, 0x0080, 0x0080};

#pragma unroll 1
  for (int m4 = 0; m4 < 32; m4 += 4) {
    const int sb = m4 >> 2;                 // readlane base (wave-uniform)
#pragma unroll
    for (int t = 0; t < 4; ++t) {
      // prefetch next step's params; final step re-reads step 31 (in-bounds)
      const float* pn = (m4 + t < 31) ? pp : pp - 768;
      f32x4 na = *(const f32x4*)(pn);
      f32x4 nb4 = *(const f32x4*)(pn + 4);
      f32x4 nc = *(const f32x4*)(pn + 8);

      f32x2 c01 = {pc[0], pc[1]}, c23 = {pc[2], pc[3]};
      f32x2 b01 = {pb[0], pb[1]}, b23 = {pb[2], pb[3]};
      f32x2 a01 = {pa[0], pa[1]}, a23 = {pa[2], pa[3]};

#pragma unroll
      for (int s = 0; s < 16; ++s) {
        float xsrc = (s < 8) ? ((const float*)&xq0)[t]
                             : ((const float*)&xq1)[t];
        float xs = rdlane(xsrc, sb + (s & 7) * 8);
        f32x2 xx = {xs, xs};
        f32x2 u01 = __builtin_elementwise_fma(
                        __builtin_elementwise_fma(c01, xx, b01), xx, a01);
        f32x2 u23 = __builtin_elementwise_fma(
                        __builtin_elementwise_fma(c23, xx, b23), xx, a23);
        uint2 at;
        at.x = pk_lo16(u01);
        at.y = pk_lo16(u23);
        // i16 clamp: wrapped/underflow patterns -> 0x0080 = min-normal bf16
        s16x4 af = __builtin_elementwise_max(__builtin_bit_cast(s16x4, at), clmp);
        f32x4 D = __builtin_amdgcn_mfma_f32_16x16x16bf16_1k(af, Qp[s], zero,
                                                            0, 0, 0);
        uint2 nq;
        nq.x = pk_bf16t(D[0], D[1]);
        nq.y = pk_bf16t(D[2], D[3]);
        Qp[s] = __builtin_bit_cast(s16x4, nq);
      }
      pa = na; pb = nb4; pc = nc;
      pp += 768;
    }
  }

  // y_s = sum_r v[r]: unpack bf16 state, sum 4, reduce across quads
  float res = 0.0f;
#pragma unroll
  for (int s = 0; s < 16; ++s) {
    uint2 qb = __builtin_bit_cast(uint2, Qp[s]);
    float v0 = __builtin_bit_cast(float, qb.x << 16);
    float v1 = __builtin_bit_cast(float, qb.x & 0xFFFF0000u);
    float v2 = __builtin_bit_cast(float, qb.y << 16);
    float v3 = __builtin_bit_cast(float, qb.y & 0xFFFF0000u);
    float t = (v0 + v1) + (v2 + v3);
    t += __shfl_xor(t, 16, 64);
    t += __shfl_xor(t, 32, 64);
    if (l == s) res = t;
  }
  if (l < 16) {
    long n0 = nb + l;
    if (n0 < (long)N) out[n0] = logf(res + EPSV);
  }
}

// ---------------------------------------------------------------------------
// Generic fallback (any M) — 8 samples/wave, rolled step loop.
// ---------------------------------------------------------------------------
__global__ __launch_bounds__(256, 4)
void tt_main_gen(const float* __restrict__ X,
                 const float* __restrict__ wk0_logits,
                 const float* __restrict__ abc,
                 float* __restrict__ out, int N, int M) {
  const int l = (int)(threadIdx.x & 63u);
  const int wave = __builtin_amdgcn_readfirstlane((int)(threadIdx.x >> 6));
  const int c = l & 15;
  const int q = l >> 4;

  long nb = ((long)blockIdx.x * 4 + wave) * 8;
  if (nb > (long)N - 8) nb = (long)N - 8;

  float wl = wk0_logits[c];
  float mx = wl;
#pragma unroll
  for (int d = 1; d < 16; d <<= 1) mx = fmaxf(mx, __shfl_xor(mx, d, 64));
  float ew = fexp2((wl - mx) * LOG2E);
  float sw = ew;
#pragma unroll
  for (int d = 1; d < 16; d <<= 1) sw += __shfl_xor(sw, d, 64);
  float w0 = ew / sw;

  f32x4 q0;
#pragma unroll
  for (int i = 0; i < 4; ++i) q0[i] = __shfl(w0, 4 * q + i, 64);
  uint2 seed;
  seed.x = pk_bf16t(q0[0], q0[1]);
  seed.y = pk_bf16t(q0[2], q0[3]);
  s16x4 Qp[8];
#pragma unroll
  for (int s = 0; s < 8; ++s) Qp[s] = __builtin_bit_cast(s16x4, seed);

  const float* Xn = X + nb * (long)M;
  const f32x4* Pm = (const f32x4*)abc + (c * 4 + q) * 3;
  f32x4 pa = Pm[0], pb = Pm[1], pc = Pm[2];
  const f32x4 zero = (f32x4){0.f, 0.f, 0.f, 0.f};
  const s16x4 clmp = (s16x4){0x0080, 0x0080, 0x0080, 0x0080};

#pragma unroll 1
  for (int m = 0; m < M; ++m) {
    f32x4 qa, qb4, qc;
    const f32x4* Pn = Pm + 192;
    bool more = (m + 1 < M);
    if (more) { qa = Pn[0]; qb4 = Pn[1]; qc = Pn[2]; }
#pragma unroll
    for (int s = 0; s < 8; ++s) {
      float xs = Xn[(long)s * M + m];
      f32x2 xx = {xs, xs};
      f32x2 c01 = {pc[0], pc[1]}, c23 = {pc[2], pc[3]};
      f32x2 b01 = {pb[0], pb[1]}, b23 = {pb[2], pb[3]};
      f32x2 a01 = {pa[0], pa[1]}, a23 = {pa[2], pa[3]};
      f32x2 u01 = __builtin_elementwise_fma(
                      __builtin_elementwise_fma(c01, xx, b01), xx, a01);
      f32x2 u23 = __builtin_elementwise_fma(
                      __builtin_elementwise_fma(c23, xx, b23), xx, a23);
      uint2 at;
      at.x = pk_lo16(u01);
      at.y = pk_lo16(u23);
      s16x4 af = __builtin_elementwise_max(__builtin_bit_cast(s16x4, at), clmp);
      f32x4 D = __builtin_amdgcn_mfma_f32_16x16x16bf16_1k(af, Qp[s], zero,
                                                          0, 0, 0);
      uint2 nq;
      nq.x = pk_bf16t(D[0], D[1]);
      nq.y = pk_bf16t(D[2], D[3]);
      Qp[s] = __builtin_bit_cast(s16x4, nq);
    }
    if (more) { pa = qa; pb = qb4; pc = qc; Pm = Pn; }
  }

  float res = 0.0f;
#pragma unroll
  for (int s = 0; s < 8; ++s) {
    uint2 qb = __builtin_bit_cast(uint2, Qp[s]);
    float v0 = __builtin_bit_cast(float, qb.x << 16);
    float v1 = __builtin_bit_cast(float, qb.x & 0xFFFF0000u);
    float v2 = __builtin_bit_cast(float, qb.y << 16);
    float v3 = __builtin_bit_cast(float, qb.y & 0xFFFF0000u);
    float t = (v0 + v1) + (v2 + v3);
    t += __shfl_xor(t, 16, 64);
    t += __shfl_xor(t, 32, 64);
    if (l == s) res = t;
  }
  if (l < 8) {
    long n0 = nb + l;
    if (n0 < (long)N) out[n0] = logf(res + EPSV);
  }
}

extern "C" void kernel_launch(void* const* d_in, const int* in_sizes, int n_in,
                              void* d_out, int out_size, void* d_ws, size_t ws_size,
                              hipStream_t stream) {
  const float* X   = (const float*)d_in[0];
  const float* wk0 = (const float*)d_in[1];
  const float* Wl  = (const float*)d_in[2];
  const float* mu  = (const float*)d_in[3];
  const float* ps  = (const float*)d_in[4];
  int K = in_sizes[1];                 // 16
  int M = in_sizes[2] / (K * K);       // 32
  int N = in_sizes[0] / M;             // 262144
  float* abc = (float*)d_ws;           // M*64*3 float4 = 96 KB

  tt_prep<<<(M * 64 + 255) / 256, 256, 0, stream>>>(Wl, mu, ps, abc, M);
  if (M == 32) {
    int blocks = (int)((N + 63) / 64);
    tt_main32<<<blocks, 256, 0, stream>>>(X, wk0, abc, (float*)d_out, N);
  } else {
    int blocks = (int)((N + 31) / 32);
    tt_main_gen<<<blocks, 256, 0, stream>>>(X, wk0, abc, (float*)d_out, N, M);
  }
}